// Round 5
// baseline (1539.271 us; speedup 1.0000x reference)
//
#include <hip/hip_runtime.h>
#include <stdint.h>

#define B_   16
#define L_   2048
#define D_   512
#define NL_  4
#define LP_  2050            // L + 2 zero-pad rows (for conv k=3)
#define TOK_ 32768           // B_*L_
#define CH_  32              // scan chunks
#define CL_  64              // chunk length = L_/CH_

typedef unsigned short u16;
typedef unsigned int   u32;

typedef float f32x4  __attribute__((ext_vector_type(4)));
typedef float f32x16 __attribute__((ext_vector_type(16)));
typedef short s16x8  __attribute__((ext_vector_type(8)));

// ---------- workspace layout (bytes) ----------
#define Y_OFF     0ull                 // y residual fp32 [32768][512]            64 MB
#define APAD_OFF  67108864ull          // Apad bf16 [16][2050][512]; scan summaries overlap
#define Z2_OFF    100696064ull         // z2 bf16 [32768][512]; gv (gated out) overlaps
#define HS_OFF    134250496ull         // hs bf16 [32768][512]; final-LN out reuses
#define G_OFF     167804928ull         // g fp32 [32768]
#define B2_OFF    167936000ull         // b' fp32 [4][1024]
#define WCV_OFF   167952384ull         // conv w' bf16 [4][512][1536]
#define WMO_OFF   174243840ull         // mo_w bf16 [4][512][512]
#define WHD_OFF   176340992ull         // head_w bf16 [512][512]
#define WOT_OFF   176865280ull         // wout^T bf16 [4][512][512]
#define WFCB_OFF  178962432ull         // fc_w bf16 [4][1024][512]
#define WC_OFF    183156736ull         // Wc = fc_w@wout bf16 [4][1024][512]
#define WS_NEED   187351040ull
// scan summaries: live only between conv-GEMM and fc-GEMM, reuse Apad space
#define ABUF_OFF  APAD_OFF             // fp32 [16][32][512] = 1 MB
#define HLOC_OFF  (APAD_OFF + 1048576ull)
#define HST_OFF   (APAD_OFF + 2097152ull)

__device__ __forceinline__ u16 f2b(float f) {
    u32 u = __float_as_uint(f);
    return (u16)((u + 0x7fffu + ((u >> 16) & 1u)) >> 16);   // RNE
}
__device__ __forceinline__ float b2f(u16 u) {
    return __uint_as_float(((u32)u) << 16);
}
__device__ __forceinline__ float sigmoidf_(float x) {
    return 1.f / (1.f + __expf(-x));
}

// async global->LDS, 16B per lane; lds base must be wave-uniform (m104/m108)
typedef const __attribute__((address_space(1))) u32 gas_u32;
typedef __attribute__((address_space(3))) u32 las_u32;
__device__ __forceinline__ void gload_lds16(const u16* g, u16* l) {
    __builtin_amdgcn_global_load_lds((gas_u32*)g, (las_u32*)l, 16, 0, 0);
}

// ---------------- sentinel (workspace too small) ----------------
__global__ void sentinel_kernel(float* o) { o[threadIdx.x] = 12345.f; }

// ---------------- embedding: y = one_hot(x) ----------------
__global__ void embed_kernel(const int* __restrict__ x, float* __restrict__ y) {
    const int idx = blockIdx.x * 256 + threadIdx.x;     // over TOK_*D_/4
    const int t  = idx >> 7;
    const int d0 = (idx & 127) * 4;
    const int tok = x[t];
    float4 v;
    v.x = (d0 + 0 == tok) ? 1.f : 0.f;
    v.y = (d0 + 1 == tok) ? 1.f : 0.f;
    v.z = (d0 + 2 == tok) ? 1.f : 0.f;
    v.w = (d0 + 3 == tok) ? 1.f : 0.f;
    ((float4*)y)[idx] = v;
}

// ---------------- merged weight prep (5 former kernels) ----------------
#define PN1 3145728   // conv repack 4*512*512*3
#define PN2 4194304   // + mo cvt   1048576
#define PN3 4456448   // + head cvt  262144
#define PN4 6553600   // + fc cvt   2097152
#define PN5 7602176   // + wo transpose 1048576
__global__ void prep_kernel(const float* __restrict__ conv_w, const float* __restrict__ mo_w,
                            const float* __restrict__ head_w, const float* __restrict__ fc_w,
                            const float* __restrict__ wout,
                            u16* __restrict__ wcv, u16* __restrict__ wmo,
                            u16* __restrict__ whd, u16* __restrict__ wfcb,
                            u16* __restrict__ woT)
{
    const int idx = blockIdx.x * 256 + threadIdx.x;
    if (idx < PN1) {
        // conv_w [4][512][512][3] (o,i,tap) -> [4][512][1536], k = tap*512 + i
        const int tap = idx % 3;
        const int rest = idx / 3;
        const int i = rest & 511;
        const int oi = rest >> 9;
        wcv[(size_t)oi * 1536 + tap * 512 + i] = f2b(conv_w[idx]);
    } else if (idx < PN2) {
        const int i = idx - PN1; wmo[i] = f2b(mo_w[i]);
    } else if (idx < PN3) {
        const int i = idx - PN2; whd[i] = f2b(head_w[i]);
    } else if (idx < PN4) {
        const int i = idx - PN3; wfcb[i] = f2b(fc_w[i]);
    } else {
        // wout [4][e=512][d=512] -> woT [4][d][e]
        const int i = idx - PN4;
        const int d = i & 511;
        const int e = (i >> 9) & 511;
        const int l = i >> 18;
        woT[((size_t)(l * 512 + d) << 9) + e] = f2b(wout[i]);
    }
}

// ---------------- LayerNorm (one wave per token), bf16 out ----------------
// pad_mode: output rows live in Apad[B][LP_][D_]; grid has 8 extra blocks that
// zero the 2 pad rows per batch (replaces the old zeropad_kernel dispatch).
__global__ __launch_bounds__(256)
void ln_kernel(const float* __restrict__ yin, const float* __restrict__ gw,
               const float* __restrict__ bw, u16* __restrict__ out, int pad_mode)
{
    if (pad_mode && blockIdx.x >= TOK_ / 4) {
        const int idx2 = (blockIdx.x - TOK_ / 4) * 256 + threadIdx.x;  // 0..2047
        const int b = idx2 >> 7;
        const int r = (idx2 >> 6) & 1;
        const int col = (idx2 & 63) * 8;
        *(uint4*)(out + ((size_t)b * LP_ + (r ? (LP_ - 1) : 0)) * D_ + col) =
            make_uint4(0, 0, 0, 0);
        return;
    }
    const int lane = threadIdx.x & 63;
    const int wave = threadIdx.x >> 6;
    const int t = blockIdx.x * 4 + wave;
    const float4* yp = (const float4*)(yin + (size_t)t * D_);
    float4 f0 = yp[lane * 2 + 0];
    float4 f1 = yp[lane * 2 + 1];
    float s  = f0.x + f0.y + f0.z + f0.w + f1.x + f1.y + f1.z + f1.w;
    float ss = f0.x*f0.x + f0.y*f0.y + f0.z*f0.z + f0.w*f0.w
             + f1.x*f1.x + f1.y*f1.y + f1.z*f1.z + f1.w*f1.w;
#pragma unroll
    for (int off = 32; off > 0; off >>= 1) {
        s  += __shfl_xor(s, off);
        ss += __shfl_xor(ss, off);
    }
    const float mean = s * (1.f / D_);
    const float inv = rsqrtf(ss * (1.f / D_) - mean * mean + 1e-5f);
    size_t orow;
    if (pad_mode) orow = ((size_t)(t >> 11) * LP_ + (t & (L_ - 1)) + 1) * D_;
    else          orow = (size_t)t * D_;
    const int d0 = lane * 8;
    float vv[8] = {f0.x, f0.y, f0.z, f0.w, f1.x, f1.y, f1.z, f1.w};
    u32 pk[4];
#pragma unroll
    for (int j = 0; j < 4; ++j) {
        u16 lo = f2b((vv[2*j]   - mean) * inv * gw[d0 + 2*j]     + bw[d0 + 2*j]);
        u16 hi = f2b((vv[2*j+1] - mean) * inv * gw[d0 + 2*j + 1] + bw[d0 + 2*j + 1]);
        pk[j] = (u32)lo | ((u32)hi << 16);
    }
    *(uint4*)(out + orow + d0) = make_uint4(pk[0], pk[1], pk[2], pk[3]);
}

// ---------------- fused gate + scan pass 1 ----------------
// block = (b, chunk): phase 1 computes the 64 gate values (wave per token),
// phase 2 runs the 64-step local recurrence for 2 d-columns per thread.
__global__ __launch_bounds__(256)
void scan1g_kernel(const u16* __restrict__ z, const float* __restrict__ wg,
                   const float* __restrict__ bg, float* __restrict__ g,
                   float* __restrict__ Abuf, float* __restrict__ Hloc)
{
    __shared__ float gs[CL_];
    const int bc = blockIdx.x;          // b*CH_ + c
    const int b = bc >> 5;
    const int c = bc & 31;
    const int tid = threadIdx.x;
    const int lane = tid & 63;
    const int wave = tid >> 6;
    const size_t zbase = ((size_t)b * L_ + c * CL_) * D_;

    const float4* wp = (const float4*)(wg + lane * 8);
    const float4 w0 = wp[0], w1 = wp[1];
    const float bgv = bg[0];
#pragma unroll 4
    for (int it = 0; it < 16; ++it) {
        const int s = wave * 16 + it;
        const u16* zp = z + zbase + (size_t)s * D_ + lane * 8;
        ushort4 z0 = *(const ushort4*)zp;
        ushort4 z1 = *(const ushort4*)(zp + 4);
        float sum = b2f(z0.x)*w0.x + b2f(z0.y)*w0.y + b2f(z0.z)*w0.z + b2f(z0.w)*w0.w
                  + b2f(z1.x)*w1.x + b2f(z1.y)*w1.y + b2f(z1.z)*w1.z + b2f(z1.w)*w1.w;
#pragma unroll
        for (int off = 32; off > 0; off >>= 1) sum += __shfl_xor(sum, off);
        if (lane == 0) {
            const float gv = sigmoidf_(sum + bgv);
            gs[s] = gv;
            g[b * L_ + c * CL_ + s] = gv;
        }
    }
    __syncthreads();
    const int d0 = tid;
    const int d1 = tid + 256;
    float h0 = 0.f, h1 = 0.f, Aa = 1.f;
#pragma unroll 4
    for (int s = 0; s < CL_; ++s) {
        const float gv = gs[s];
        const float a = 1.f - gv;
        h0 = a * h0 + gv * b2f(z[zbase + (size_t)s * D_ + d0]);
        h1 = a * h1 + gv * b2f(z[zbase + (size_t)s * D_ + d1]);
        Aa *= a;
    }
    const int o = bc * D_;
    Abuf[o + d0] = Aa;  Abuf[o + d1] = Aa;
    Hloc[o + d0] = h0;  Hloc[o + d1] = h1;
}

__global__ __launch_bounds__(256)
void scan2_kernel(const float* __restrict__ Abuf, const float* __restrict__ Hloc,
                  float* __restrict__ Hstart)
{
    const int idx = blockIdx.x * 256 + threadIdx.x;     // B*D
    const int d = idx & 511;
    const int b = idx >> 9;
    float H = 0.f;
#pragma unroll
    for (int c = 0; c < CH_; ++c) {
        const int o = (b * CH_ + c) * D_ + d;
        Hstart[o] = H;
        H = Abuf[o] * H + Hloc[o];
    }
}

__global__ __launch_bounds__(256)
void scan3_kernel(const u16* __restrict__ z, const float* __restrict__ g,
                  const float* __restrict__ Hstart, u16* __restrict__ hs)
{
    const int idx = blockIdx.x * 256 + threadIdx.x;     // B*CH*D
    const int d = idx & 511;
    const int c = (idx >> 9) & (CH_ - 1);
    const int b = idx >> 14;
    const u16* zp = z + ((size_t)b * L_ + c * CL_) * D_ + d;
    const float* gp = g + b * L_ + c * CL_;
    u16* hp = hs + ((size_t)b * L_ + c * CL_) * D_ + d;
    float h = Hstart[idx];
#pragma unroll 4
    for (int s = 0; s < CL_; ++s) {
        const float gv = gp[s];
        h = (1.f - gv) * h + gv * b2f(zp[(size_t)s * D_]);
        hp[(size_t)s * D_] = f2b(h);
    }
}

// b'[l][f] = sum_e fc_w[l][f][e]*bout[l][e] + fc_b[l][f]; one wave per (l,f)
__global__ __launch_bounds__(256)
void bias2_kernel(const float* __restrict__ fcw, const float* __restrict__ bout,
                  const float* __restrict__ fcb, float* __restrict__ b2)
{
    const int lane = threadIdx.x & 63;
    const int wave = threadIdx.x >> 6;
    const int f = blockIdx.x * 4 + wave;                // 0..4095
    const int l = f >> 10;
    const float4* wp = (const float4*)(fcw + (size_t)f * 512 + lane * 8);
    const float4* bp = (const float4*)(bout + l * 512 + lane * 8);
    float4 w0 = wp[0], w1 = wp[1], v0 = bp[0], v1 = bp[1];
    float s = w0.x*v0.x + w0.y*v0.y + w0.z*v0.z + w0.w*v0.w
            + w1.x*v1.x + w1.y*v1.y + w1.z*v1.z + w1.w*v1.w;
#pragma unroll
    for (int off = 32; off > 0; off >>= 1) s += __shfl_xor(s, off);
    if (lane == 0) b2[f] = s + fcb[f];
}

// ---------------- bf16 MFMA GEMM: C[M,N] = A[M,K] @ W[N,K]^T (+bias,+residual) ----------------
// 128x128 tile, BK=64, 4 waves each 64x64 via 2x2 of 32x32x16 MFMA (halves MFMA
// instr count vs 16x16x32 at same LDS traffic). XOR-swizzled staging: lane i
// fetches global chunk ((i&7)^(i>>3)); fragment reads de-swizzle with row&7.
// Conflict-free per 8-lane phase (8 distinct row&7 per phase).
#define BM 128
#define BN 128
#define BK 64

#define MFMA32(a, b, c) __builtin_amdgcn_mfma_f32_32x32x16_bf16(a, b, c, 0, 0, 0)

__global__ __launch_bounds__(256)
void gemm_bt(const u16* __restrict__ A, const u16* __restrict__ W,
             const float* __restrict__ bias, const float* __restrict__ residual,
             float* __restrict__ outF, u16* __restrict__ outB,
             int N, int K, int a_stride, int conv_mode,
             int az, int wz, int oz)
{
    __shared__ u16 As[BM][BK];
    __shared__ u16 Bs[BN][BK];

    const int tid  = threadIdx.x;
    const int lane = tid & 63;
    const int wave = tid >> 6;
    const int m0 = blockIdx.x * BM;
    const int n0 = blockIdx.y * BN;
    const int zb = blockIdx.z;

    size_t a_base;
    if (conv_mode) {
        const int b = m0 >> 11;
        const int l = m0 & (L_ - 1);
        a_base = ((size_t)b * LP_ + l) * D_;
    } else {
        a_base = (size_t)m0 * a_stride;
    }
    const u16* Ap = A + a_base + (size_t)zb * az;
    const u16* Wp = W + (size_t)n0 * K + (size_t)zb * wz;

    f32x16 acc[2][2];
#pragma unroll
    for (int i = 0; i < 2; ++i)
#pragma unroll
        for (int j = 0; j < 2; ++j)
#pragma unroll
            for (int r = 0; r < 16; ++r) acc[i][j][r] = 0.f;

    const int wm = (wave & 1) * 64;
    const int wn = (wave >> 1) * 64;
    const int srow_l = lane >> 3;                       // 0..7
    const int scol   = ((lane & 7) ^ srow_l) << 3;      // swizzled global chunk
    u16* asBase = &As[0][0] + wave * 512;
    u16* bsBase = &Bs[0][0] + wave * 512;

    const int lrow  = lane & 31;                        // m/n within 32-tile
    const int khalf = (lane >> 5) * 8;
    const int sw    = lane & 7;                         // fragment row&7

    for (int k0 = 0; k0 < K; k0 += BK) {
        __syncthreads();
#pragma unroll
        for (int it = 0; it < 4; ++it) {
            const int row = it * 32 + wave * 8 + srow_l;
            gload_lds16(Ap + (size_t)row * a_stride + k0 + scol, asBase + it * 2048);
            gload_lds16(Wp + (size_t)row * K        + k0 + scol, bsBase + it * 2048);
        }
        __syncthreads();
#pragma unroll
        for (int kk = 0; kk < BK; kk += 16) {
            const int kcol = kk + khalf;
            const int koff = (((kcol >> 3) ^ sw) << 3);   // de-swizzled chunk
            s16x8 af0 = *(const s16x8*)(&As[wm + lrow][koff]);
            s16x8 af1 = *(const s16x8*)(&As[wm + 32 + lrow][koff]);
            s16x8 bf0 = *(const s16x8*)(&Bs[wn + lrow][koff]);
            s16x8 bf1 = *(const s16x8*)(&Bs[wn + 32 + lrow][koff]);
            acc[0][0] = MFMA32(af0, bf0, acc[0][0]);
            acc[0][1] = MFMA32(af0, bf1, acc[0][1]);
            acc[1][0] = MFMA32(af1, bf0, acc[1][0]);
            acc[1][1] = MFMA32(af1, bf1, acc[1][1]);
        }
    }

    // epilogue: 32x32 C/D layout col=lane&31, row=(reg&3)+8*(reg>>2)+4*(lane>>5) [m74/m101]
    const int col_l = lane & 31;
    const int rbase = (lane >> 5) * 4;
#pragma unroll
    for (int j = 0; j < 2; ++j) {
        const int col = n0 + wn + j * 32 + col_l;
        const float bv = bias ? bias[col] : 0.f;
#pragma unroll
        for (int i = 0; i < 2; ++i) {
#pragma unroll
            for (int r = 0; r < 16; ++r) {
                const int row = m0 + wm + i * 32 + (r & 3) + 8 * (r >> 2) + rbase;
                const size_t off = (size_t)row * N + col + (size_t)zb * oz;
                float v = acc[i][j][r] + bv;
                if (residual) v += residual[off];
                if (outF) outF[off] = v;
                else      outB[off] = f2b(v);
            }
        }
    }
}

// ---------------- fused fc GEMM + sigmoid gate (same structure) ----------------
__global__ __launch_bounds__(256, 2)
void gemm_fc(const u16* __restrict__ A, const u16* __restrict__ Wc,
             const float* __restrict__ b2, u16* __restrict__ out)
{
    __shared__ u16 As[BM][BK];
    __shared__ u16 Bg[BN][BK];
    __shared__ u16 Bv[BN][BK];

    const int tid  = threadIdx.x;
    const int lane = tid & 63;
    const int wave = tid >> 6;
    const int m0 = blockIdx.x * BM;
    const int n0 = blockIdx.y * BN;

    const u16* Ap = A + (size_t)m0 * 512;
    const u16* Wg = Wc + (size_t)n0 * 512;
    const u16* Wv = Wc + (size_t)(n0 + 512) * 512;

    f32x16 accg[2][2], accv[2][2];
#pragma unroll
    for (int i = 0; i < 2; ++i)
#pragma unroll
        for (int j = 0; j < 2; ++j)
#pragma unroll
            for (int r = 0; r < 16; ++r) { accg[i][j][r] = 0.f; accv[i][j][r] = 0.f; }

    const int wm = (wave & 1) * 64;
    const int wn = (wave >> 1) * 64;
    const int srow_l = lane >> 3;
    const int scol   = ((lane & 7) ^ srow_l) << 3;
    u16* aB = &As[0][0] + wave * 512;
    u16* gB = &Bg[0][0] + wave * 512;
    u16* vB = &Bv[0][0] + wave * 512;

    const int lrow  = lane & 31;
    const int khalf = (lane >> 5) * 8;
    const int sw    = lane & 7;

    for (int k0 = 0; k0 < 512; k0 += BK) {
        __syncthreads();
#pragma unroll
        for (int it = 0; it < 4; ++it) {
            const int row = it * 32 + wave * 8 + srow_l;
            gload_lds16(Ap + (size_t)row * 512 + k0 + scol, aB + it * 2048);
            gload_lds16(Wg + (size_t)row * 512 + k0 + scol, gB + it * 2048);
            gload_lds16(Wv + (size_t)row * 512 + k0 + scol, vB + it * 2048);
        }
        __syncthreads();
#pragma unroll
        for (int kk = 0; kk < BK; kk += 16) {
            const int kcol = kk + khalf;
            const int koff = (((kcol >> 3) ^ sw) << 3);
            s16x8 af0 = *(const s16x8*)(&As[wm + lrow][koff]);
            s16x8 af1 = *(const s16x8*)(&As[wm + 32 + lrow][koff]);
            s16x8 bg0 = *(const s16x8*)(&Bg[wn + lrow][koff]);
            s16x8 bg1 = *(const s16x8*)(&Bg[wn + 32 + lrow][koff]);
            s16x8 bv0 = *(const s16x8*)(&Bv[wn + lrow][koff]);
            s16x8 bv1 = *(const s16x8*)(&Bv[wn + 32 + lrow][koff]);
            accg[0][0] = MFMA32(af0, bg0, accg[0][0]);
            accg[0][1] = MFMA32(af0, bg1, accg[0][1]);
            accg[1][0] = MFMA32(af1, bg0, accg[1][0]);
            accg[1][1] = MFMA32(af1, bg1, accg[1][1]);
            accv[0][0] = MFMA32(af0, bv0, accv[0][0]);
            accv[0][1] = MFMA32(af0, bv1, accv[0][1]);
            accv[1][0] = MFMA32(af1, bv0, accv[1][0]);
            accv[1][1] = MFMA32(af1, bv1, accv[1][1]);
        }
    }

    const int col_l = lane & 31;
    const int rbase = (lane >> 5) * 4;
#pragma unroll
    for (int j = 0; j < 2; ++j) {
        const int col = n0 + wn + j * 32 + col_l;
        const float bg_ = b2[col];
        const float bv_ = b2[col + 512];
#pragma unroll
        for (int i = 0; i < 2; ++i) {
#pragma unroll
            for (int r = 0; r < 16; ++r) {
                const int row = m0 + wm + i * 32 + (r & 3) + 8 * (r >> 2) + rbase;
                const float gval = sigmoidf_(accg[i][j][r] + bg_);
                const float vval = accv[i][j][r] + bv_;
                out[(size_t)row * 512 + col] = f2b(gval * vval);
            }
        }
    }
}

extern "C" void kernel_launch(void* const* d_in, const int* in_sizes, int n_in,
                              void* d_out, int out_size, void* d_ws, size_t ws_size,
                              hipStream_t stream)
{
    const int*   x      = (const int*)d_in[0];
    const float* ln_g   = (const float*)d_in[1];
    const float* ln_b   = (const float*)d_in[2];
    const float* conv_w = (const float*)d_in[3];
    const float* conv_b = (const float*)d_in[4];
    const float* wg     = (const float*)d_in[5];
    const float* bg     = (const float*)d_in[6];
    const float* wout   = (const float*)d_in[7];
    const float* bout   = (const float*)d_in[8];
    const float* fc_w   = (const float*)d_in[9];
    const float* fc_b   = (const float*)d_in[10];
    const float* mo_w   = (const float*)d_in[11];
    const float* mo_b   = (const float*)d_in[12];
    const float* lnf_g  = (const float*)d_in[13];
    const float* lnf_b  = (const float*)d_in[14];
    const float* head_w = (const float*)d_in[15];
    const float* head_b = (const float*)d_in[16];

    if (ws_size < WS_NEED) {
        sentinel_kernel<<<1, 256, 0, stream>>>((float*)d_out);
        return;
    }

    char* ws = (char*)d_ws;
    float* y    = (float*)(ws + Y_OFF);
    u16*   apad = (u16*)(ws + APAD_OFF);
    u16*   z2b  = (u16*)(ws + Z2_OFF);        // conv out bf16; gv (gated) overlaps after scan
    u16*   gv   = (u16*)(ws + Z2_OFF);
    u16*   hs   = (u16*)(ws + HS_OFF);        // scan out; final-LN out reuses
    float* gbuf = (float*)(ws + G_OFF);
    float* b2   = (float*)(ws + B2_OFF);
    float* Abuf = (float*)(ws + ABUF_OFF);
    float* Hloc = (float*)(ws + HLOC_OFF);
    float* Hst  = (float*)(ws + HST_OFF);
    u16*   wcv  = (u16*)(ws + WCV_OFF);
    u16*   wmo  = (u16*)(ws + WMO_OFF);
    u16*   whd  = (u16*)(ws + WHD_OFF);
    u16*   woT  = (u16*)(ws + WOT_OFF);
    u16*   wfcb = (u16*)(ws + WFCB_OFF);
    u16*   wc   = (u16*)(ws + WC_OFF);

    // merged weight conversion + Wc precompute
    prep_kernel<<<PN5 / 256, 256, 0, stream>>>(conv_w, mo_w, head_w, fc_w, wout,
                                               wcv, wmo, whd, wfcb, woT);
    gemm_bt<<<dim3(8, 4, 4), 256, 0, stream>>>(wfcb, woT, nullptr, nullptr,
            nullptr, wc, 512, 512, 512, 0, 1024*512, 512*512, 1024*512);
    bias2_kernel<<<(NL_*1024)/4, 256, 0, stream>>>(fc_w, bout, fc_b, b2);

    embed_kernel<<<(TOK_*D_/4)/256, 256, 0, stream>>>(x, y);

    for (int l = 0; l < NL_; ++l) {
        // ln with 8 extra blocks zeroing the conv pad rows
        ln_kernel<<<TOK_/4 + 8, 256, 0, stream>>>(y, ln_g + l*512, ln_b + l*512, apad, 1);
        // conv1d as im2col GEMM: K=1536, lda=512 (rows overlap), bf16 out z2b
        gemm_bt<<<dim3(256, 4), 256, 0, stream>>>(apad, wcv + (size_t)l*512*1536,
                conv_b + l*512, nullptr, nullptr, z2b, 512, 1536, 512, 1, 0, 0, 0);
        // fused gate + scan pass 1
        scan1g_kernel<<<B_*CH_, 256, 0, stream>>>(z2b, wg + l*512, bg + l, gbuf, Abuf, Hloc);
        scan2_kernel<<<(B_*D_)/256, 256, 0, stream>>>(Abuf, Hloc, Hst);
        scan3_kernel<<<(B_*CH_*D_)/256, 256, 0, stream>>>(z2b, gbuf, Hst, hs);
        // merged wout+fc GEMM with fused sigmoid-gate; writes gv (z2 region, z2 dead)
        gemm_fc<<<dim3(256, 4), 256, 0, stream>>>(hs, wc + (size_t)l*1024*512,
                b2 + l*1024, gv);
        // mo: fp32 out with residual read+write on y
        gemm_bt<<<dim3(256, 4), 256, 0, stream>>>(gv, wmo + (size_t)l*512*512,
                mo_b + l*512, y, y, nullptr, 512, 512, 512, 0, 0, 0, 0);
    }

    // final LN (bf16 into hs, dead) + head GEMM -> d_out fp32
    ln_kernel<<<TOK_/4, 256, 0, stream>>>(y, lnf_g, lnf_b, hs, 0);
    gemm_bt<<<dim3(256, 4), 256, 0, stream>>>(hs, whd, head_b, nullptr,
            (float*)d_out, nullptr, 512, 512, 512, 0, 0, 0, 0);

    (void)in_sizes; (void)n_in; (void)out_size;
}

// Round 6
// 1015.743 us; speedup vs baseline: 1.5154x; 1.5154x over previous
//
#include <hip/hip_runtime.h>
#include <stdint.h>

#define B_   16
#define L_   2048
#define D_   512
#define NL_  4
#define LP_  2050            // L + 2 zero-pad rows (for conv k=3)
#define TOK_ 32768           // B_*L_
#define CH_  32              // scan chunks
#define CL_  64              // chunk length = L_/CH_

typedef unsigned short u16;
typedef unsigned int   u32;

typedef float f32x4 __attribute__((ext_vector_type(4)));
typedef short s16x8 __attribute__((ext_vector_type(8)));

// ---------- workspace layout (bytes) ----------
#define Y_OFF     0ull                 // y residual BF16 [32768][512]            32 MB
#define APAD_OFF  67108864ull          // Apad bf16 [16][2050][512]; scan summaries overlap
#define Z2_OFF    100696064ull         // z2 bf16 [32768][512]; gv (gated out) overlaps
#define HS_OFF    134250496ull         // hs bf16 [32768][512]; final-LN out reuses
#define G_OFF     167804928ull         // g fp32 [32768]
#define B2_OFF    167936000ull         // b' fp32 [4][1024]
#define WCV_OFF   167952384ull         // conv w' bf16 [4][512][1536]
#define WMO_OFF   174243840ull         // mo_w bf16 [4][512][512]
#define WHD_OFF   176340992ull         // head_w bf16 [512][512]
#define WOT_OFF   176865280ull         // wout^T bf16 [4][512][512]
#define WFCB_OFF  178962432ull         // fc_w bf16 [4][1024][512]
#define WC_OFF    183156736ull         // Wc = fc_w@wout bf16 [4][1024][512]
#define WS_NEED   187351040ull
// scan summaries: live only between conv-GEMM and fc-GEMM, reuse Apad space
#define ABUF_OFF  APAD_OFF             // fp32 [16][32][512] = 1 MB
#define HLOC_OFF  (APAD_OFF + 1048576ull)
#define HST_OFF   (APAD_OFF + 2097152ull)

__device__ __forceinline__ u16 f2b(float f) {
    u32 u = __float_as_uint(f);
    return (u16)((u + 0x7fffu + ((u >> 16) & 1u)) >> 16);   // RNE
}
__device__ __forceinline__ float b2f(u16 u) {
    return __uint_as_float(((u32)u) << 16);
}
__device__ __forceinline__ float sigmoidf_(float x) {
    return 1.f / (1.f + __expf(-x));
}

// async global->LDS, 16B per lane; lds base must be wave-uniform (m104/m108)
typedef const __attribute__((address_space(1))) u32 gas_u32;
typedef __attribute__((address_space(3))) u32 las_u32;
__device__ __forceinline__ void gload_lds16(const u16* g, u16* l) {
    __builtin_amdgcn_global_load_lds((gas_u32*)g, (las_u32*)l, 16, 0, 0);
}

// ---------------- sentinel (workspace too small) ----------------
__global__ void sentinel_kernel(float* o) { o[threadIdx.x] = 12345.f; }

// ---------------- embedding: y = one_hot(x) in bf16 (exact) ----------------
__global__ void embed_kernel(const int* __restrict__ x, u16* __restrict__ y) {
    const int idx = blockIdx.x * 256 + threadIdx.x;     // over TOK_*D_/8
    const int t  = idx >> 6;
    const int d0 = (idx & 63) * 8;
    const int tok = x[t];
    ushort4 lo, hi;
    lo.x = (d0 + 0 == tok) ? 0x3F80 : 0;  lo.y = (d0 + 1 == tok) ? 0x3F80 : 0;
    lo.z = (d0 + 2 == tok) ? 0x3F80 : 0;  lo.w = (d0 + 3 == tok) ? 0x3F80 : 0;
    hi.x = (d0 + 4 == tok) ? 0x3F80 : 0;  hi.y = (d0 + 5 == tok) ? 0x3F80 : 0;
    hi.z = (d0 + 6 == tok) ? 0x3F80 : 0;  hi.w = (d0 + 7 == tok) ? 0x3F80 : 0;
    u16* p = y + (size_t)t * D_ + d0;
    *(ushort4*)p = lo;
    *(ushort4*)(p + 4) = hi;
}

// ---------------- merged weight prep (5 former kernels) ----------------
#define PN1 3145728   // conv repack 4*512*512*3
#define PN2 4194304   // + mo cvt   1048576
#define PN3 4456448   // + head cvt  262144
#define PN4 6553600   // + fc cvt   2097152
#define PN5 7602176   // + wo transpose 1048576
__global__ void prep_kernel(const float* __restrict__ conv_w, const float* __restrict__ mo_w,
                            const float* __restrict__ head_w, const float* __restrict__ fc_w,
                            const float* __restrict__ wout,
                            u16* __restrict__ wcv, u16* __restrict__ wmo,
                            u16* __restrict__ whd, u16* __restrict__ wfcb,
                            u16* __restrict__ woT)
{
    const int idx = blockIdx.x * 256 + threadIdx.x;
    if (idx < PN1) {
        // conv_w [4][512][512][3] (o,i,tap) -> [4][512][1536], k = tap*512 + i
        const int tap = idx % 3;
        const int rest = idx / 3;
        const int i = rest & 511;
        const int oi = rest >> 9;
        wcv[(size_t)oi * 1536 + tap * 512 + i] = f2b(conv_w[idx]);
    } else if (idx < PN2) {
        const int i = idx - PN1; wmo[i] = f2b(mo_w[i]);
    } else if (idx < PN3) {
        const int i = idx - PN2; whd[i] = f2b(head_w[i]);
    } else if (idx < PN4) {
        const int i = idx - PN3; wfcb[i] = f2b(fc_w[i]);
    } else {
        // wout [4][e=512][d=512] -> woT [4][d][e]
        const int i = idx - PN4;
        const int d = i & 511;
        const int e = (i >> 9) & 511;
        const int l = i >> 18;
        woT[((size_t)(l * 512 + d) << 9) + e] = f2b(wout[i]);
    }
}

// ---------------- LayerNorm (one wave per token), bf16 in/out ----------------
// pad_mode: output rows live in Apad[B][LP_][D_]; grid has 8 extra blocks that
// zero the 2 pad rows per batch.
__global__ __launch_bounds__(256)
void ln_kernel(const u16* __restrict__ yin, const float* __restrict__ gw,
               const float* __restrict__ bw, u16* __restrict__ out, int pad_mode)
{
    if (pad_mode && blockIdx.x >= TOK_ / 4) {
        const int idx2 = (blockIdx.x - TOK_ / 4) * 256 + threadIdx.x;  // 0..2047
        const int b = idx2 >> 7;
        const int r = (idx2 >> 6) & 1;
        const int col = (idx2 & 63) * 8;
        *(uint4*)(out + ((size_t)b * LP_ + (r ? (LP_ - 1) : 0)) * D_ + col) =
            make_uint4(0, 0, 0, 0);
        return;
    }
    const int lane = threadIdx.x & 63;
    const int wave = threadIdx.x >> 6;
    const int t = blockIdx.x * 4 + wave;
    const u16* yp = yin + (size_t)t * D_ + lane * 8;
    ushort4 a0 = *(const ushort4*)yp;
    ushort4 a1 = *(const ushort4*)(yp + 4);
    float vv[8] = {b2f(a0.x), b2f(a0.y), b2f(a0.z), b2f(a0.w),
                   b2f(a1.x), b2f(a1.y), b2f(a1.z), b2f(a1.w)};
    float s = 0.f, ss = 0.f;
#pragma unroll
    for (int j = 0; j < 8; ++j) { s += vv[j]; ss += vv[j] * vv[j]; }
#pragma unroll
    for (int off = 32; off > 0; off >>= 1) {
        s  += __shfl_xor(s, off);
        ss += __shfl_xor(ss, off);
    }
    const float mean = s * (1.f / D_);
    const float inv = rsqrtf(ss * (1.f / D_) - mean * mean + 1e-5f);
    size_t orow;
    if (pad_mode) orow = ((size_t)(t >> 11) * LP_ + (t & (L_ - 1)) + 1) * D_;
    else          orow = (size_t)t * D_;
    const int d0 = lane * 8;
    u32 pk[4];
#pragma unroll
    for (int j = 0; j < 4; ++j) {
        u16 lo = f2b((vv[2*j]   - mean) * inv * gw[d0 + 2*j]     + bw[d0 + 2*j]);
        u16 hi = f2b((vv[2*j+1] - mean) * inv * gw[d0 + 2*j + 1] + bw[d0 + 2*j + 1]);
        pk[j] = (u32)lo | ((u32)hi << 16);
    }
    *(uint4*)(out + orow + d0) = make_uint4(pk[0], pk[1], pk[2], pk[3]);
}

// ---------------- fused gate + scan pass 1 ----------------
__global__ __launch_bounds__(256)
void scan1g_kernel(const u16* __restrict__ z, const float* __restrict__ wg,
                   const float* __restrict__ bg, float* __restrict__ g,
                   float* __restrict__ Abuf, float* __restrict__ Hloc)
{
    __shared__ float gs[CL_];
    const int bc = blockIdx.x;          // b*CH_ + c
    const int b = bc >> 5;
    const int c = bc & 31;
    const int tid = threadIdx.x;
    const int lane = tid & 63;
    const int wave = tid >> 6;
    const size_t zbase = ((size_t)b * L_ + c * CL_) * D_;

    const float4* wp = (const float4*)(wg + lane * 8);
    const float4 w0 = wp[0], w1 = wp[1];
    const float bgv = bg[0];
#pragma unroll 4
    for (int it = 0; it < 16; ++it) {
        const int s = wave * 16 + it;
        const u16* zp = z + zbase + (size_t)s * D_ + lane * 8;
        ushort4 z0 = *(const ushort4*)zp;
        ushort4 z1 = *(const ushort4*)(zp + 4);
        float sum = b2f(z0.x)*w0.x + b2f(z0.y)*w0.y + b2f(z0.z)*w0.z + b2f(z0.w)*w0.w
                  + b2f(z1.x)*w1.x + b2f(z1.y)*w1.y + b2f(z1.z)*w1.z + b2f(z1.w)*w1.w;
#pragma unroll
        for (int off = 32; off > 0; off >>= 1) sum += __shfl_xor(sum, off);
        if (lane == 0) {
            const float gv = sigmoidf_(sum + bgv);
            gs[s] = gv;
            g[b * L_ + c * CL_ + s] = gv;
        }
    }
    __syncthreads();
    const int d0 = tid;
    const int d1 = tid + 256;
    float h0 = 0.f, h1 = 0.f, Aa = 1.f;
#pragma unroll 4
    for (int s = 0; s < CL_; ++s) {
        const float gv = gs[s];
        const float a = 1.f - gv;
        h0 = a * h0 + gv * b2f(z[zbase + (size_t)s * D_ + d0]);
        h1 = a * h1 + gv * b2f(z[zbase + (size_t)s * D_ + d1]);
        Aa *= a;
    }
    const int o = bc * D_;
    Abuf[o + d0] = Aa;  Abuf[o + d1] = Aa;
    Hloc[o + d0] = h0;  Hloc[o + d1] = h1;
}

__global__ __launch_bounds__(256)
void scan2_kernel(const float* __restrict__ Abuf, const float* __restrict__ Hloc,
                  float* __restrict__ Hstart)
{
    const int idx = blockIdx.x * 256 + threadIdx.x;     // B*D
    const int d = idx & 511;
    const int b = idx >> 9;
    float H = 0.f;
#pragma unroll
    for (int c = 0; c < CH_; ++c) {
        const int o = (b * CH_ + c) * D_ + d;
        Hstart[o] = H;
        H = Abuf[o] * H + Hloc[o];
    }
}

__global__ __launch_bounds__(256)
void scan3_kernel(const u16* __restrict__ z, const float* __restrict__ g,
                  const float* __restrict__ Hstart, u16* __restrict__ hs)
{
    const int idx = blockIdx.x * 256 + threadIdx.x;     // B*CH*D
    const int d = idx & 511;
    const int c = (idx >> 9) & (CH_ - 1);
    const int b = idx >> 14;
    const u16* zp = z + ((size_t)b * L_ + c * CL_) * D_ + d;
    const float* gp = g + b * L_ + c * CL_;
    u16* hp = hs + ((size_t)b * L_ + c * CL_) * D_ + d;
    float h = Hstart[idx];
#pragma unroll 4
    for (int s = 0; s < CL_; ++s) {
        const float gv = gp[s];
        h = (1.f - gv) * h + gv * b2f(zp[(size_t)s * D_]);
        hp[(size_t)s * D_] = f2b(h);
    }
}

// b'[l][f] = sum_e fc_w[l][f][e]*bout[l][e] + fc_b[l][f]; one wave per (l,f)
__global__ __launch_bounds__(256)
void bias2_kernel(const float* __restrict__ fcw, const float* __restrict__ bout,
                  const float* __restrict__ fcb, float* __restrict__ b2)
{
    const int lane = threadIdx.x & 63;
    const int wave = threadIdx.x >> 6;
    const int f = blockIdx.x * 4 + wave;                // 0..4095
    const int l = f >> 10;
    const float4* wp = (const float4*)(fcw + (size_t)f * 512 + lane * 8);
    const float4* bp = (const float4*)(bout + l * 512 + lane * 8);
    float4 w0 = wp[0], w1 = wp[1], v0 = bp[0], v1 = bp[1];
    float s = w0.x*v0.x + w0.y*v0.y + w0.z*v0.z + w0.w*v0.w
            + w1.x*v1.x + w1.y*v1.y + w1.z*v1.z + w1.w*v1.w;
#pragma unroll
    for (int off = 32; off > 0; off >>= 1) s += __shfl_xor(s, off);
    if (lane == 0) b2[f] = s + fcb[f];
}

// ---------------- bf16 MFMA GEMM: C[M,N] = A[M,K] @ W[N,K]^T (+bias,+bf16 residual) ----------------
// Round-4 verified structure: 128x128 tile, BK=64, 4 waves each 64x64 via 4x4 of
// 16x16x32 MFMA (VGPR 112, SQ_LDS_BANK_CONFLICT=0 — do NOT switch to 32x32x16:
// its fragment pattern is 4 lanes/chunk per 32-lane group = conflicts, +36 VGPR).
// XOR-swizzled staging: lane i fetches global chunk ((i&7)^(i>>3)); fragment
// reads de-swizzle with row&7 (2 lanes/chunk = free, m136).
#define BM 128
#define BN 128
#define BK 64

__global__ __launch_bounds__(256)
void gemm_bt(const u16* __restrict__ A, const u16* __restrict__ W,
             const float* __restrict__ bias, const u16* __restrict__ resB,
             float* __restrict__ outF, u16* __restrict__ outB,
             int N, int K, int a_stride, int conv_mode,
             int az, int wz, int oz)
{
    __shared__ u16 As[BM][BK];
    __shared__ u16 Bs[BN][BK];

    const int tid  = threadIdx.x;
    const int lane = tid & 63;
    const int wave = tid >> 6;
    const int m0 = blockIdx.x * BM;
    const int n0 = blockIdx.y * BN;
    const int zb = blockIdx.z;

    size_t a_base;
    if (conv_mode) {
        const int b = m0 >> 11;
        const int l = m0 & (L_ - 1);
        a_base = ((size_t)b * LP_ + l) * D_;
    } else {
        a_base = (size_t)m0 * a_stride;
    }
    const u16* Ap = A + a_base + (size_t)zb * az;
    const u16* Wp = W + (size_t)n0 * K + (size_t)zb * wz;

    f32x4 acc[4][4];
#pragma unroll
    for (int i = 0; i < 4; ++i)
#pragma unroll
        for (int j = 0; j < 4; ++j)
#pragma unroll
            for (int r = 0; r < 4; ++r) acc[i][j][r] = 0.f;

    const int wm = (wave & 1) * 64;
    const int wn = (wave >> 1) * 64;
    const int srow_l = lane >> 3;                       // 0..7
    const int scol   = ((lane & 7) ^ srow_l) << 3;      // swizzled global chunk
    u16* asBase = &As[0][0] + wave * 512;
    u16* bsBase = &Bs[0][0] + wave * 512;

    for (int k0 = 0; k0 < K; k0 += BK) {
        __syncthreads();
#pragma unroll
        for (int it = 0; it < 4; ++it) {
            const int row = it * 32 + wave * 8 + srow_l;
            gload_lds16(Ap + (size_t)row * a_stride + k0 + scol, asBase + it * 2048);
            gload_lds16(Wp + (size_t)row * K        + k0 + scol, bsBase + it * 2048);
        }
        __syncthreads();
        const int krow = lane & 15;
        const int sw = krow & 7;
#pragma unroll
        for (int kk = 0; kk < BK; kk += 32) {
            const int kcol = kk + ((lane >> 4) << 3);
            const int koff = (((kcol >> 3) ^ sw) << 3);   // de-swizzled chunk
            s16x8 af[4], bfr[4];
#pragma unroll
            for (int i = 0; i < 4; ++i)
                af[i] = *(const s16x8*)(&As[wm + i * 16 + krow][koff]);
#pragma unroll
            for (int j = 0; j < 4; ++j)
                bfr[j] = *(const s16x8*)(&Bs[wn + j * 16 + krow][koff]);
#pragma unroll
            for (int i = 0; i < 4; ++i)
#pragma unroll
                for (int j = 0; j < 4; ++j)
                    acc[i][j] = __builtin_amdgcn_mfma_f32_16x16x32_bf16(af[i], bfr[j], acc[i][j], 0, 0, 0);
        }
    }

    // epilogue: C/D layout col=lane&15, row=(lane>>4)*4+reg  [verified m89/m91]
    const int col_l = lane & 15;
    const int row_q = (lane >> 4) * 4;
#pragma unroll
    for (int j = 0; j < 4; ++j) {
        const int col = n0 + wn + j * 16 + col_l;
        const float bv = bias ? bias[col] : 0.f;
#pragma unroll
        for (int i = 0; i < 4; ++i) {
#pragma unroll
            for (int r = 0; r < 4; ++r) {
                const int row = m0 + wm + i * 16 + row_q + r;
                const size_t off = (size_t)row * N + col + (size_t)zb * oz;
                float v = acc[i][j][r] + bv;
                if (resB) v += b2f(resB[off]);
                if (outF) outF[off] = v;
                else      outB[off] = f2b(v);
            }
        }
    }
}

// ---------------- fused fc GEMM + sigmoid gate (round-4 structure) ----------------
__global__ __launch_bounds__(256, 2)
void gemm_fc(const u16* __restrict__ A, const u16* __restrict__ Wc,
             const float* __restrict__ b2, u16* __restrict__ out)
{
    __shared__ u16 As[BM][BK];
    __shared__ u16 Bg[BN][BK];
    __shared__ u16 Bv[BN][BK];

    const int tid  = threadIdx.x;
    const int lane = tid & 63;
    const int wave = tid >> 6;
    const int m0 = blockIdx.x * BM;
    const int n0 = blockIdx.y * BN;

    const u16* Ap = A + (size_t)m0 * 512;
    const u16* Wg = Wc + (size_t)n0 * 512;
    const u16* Wv = Wc + (size_t)(n0 + 512) * 512;

    f32x4 accg[4][4], accv[4][4];
#pragma unroll
    for (int i = 0; i < 4; ++i)
#pragma unroll
        for (int j = 0; j < 4; ++j)
#pragma unroll
            for (int r = 0; r < 4; ++r) { accg[i][j][r] = 0.f; accv[i][j][r] = 0.f; }

    const int wm = (wave & 1) * 64;
    const int wn = (wave >> 1) * 64;
    const int srow_l = lane >> 3;
    const int scol   = ((lane & 7) ^ srow_l) << 3;
    u16* aB = &As[0][0] + wave * 512;
    u16* gB = &Bg[0][0] + wave * 512;
    u16* vB = &Bv[0][0] + wave * 512;

    for (int k0 = 0; k0 < 512; k0 += BK) {
        __syncthreads();
#pragma unroll
        for (int it = 0; it < 4; ++it) {
            const int row = it * 32 + wave * 8 + srow_l;
            gload_lds16(Ap + (size_t)row * 512 + k0 + scol, aB + it * 2048);
            gload_lds16(Wg + (size_t)row * 512 + k0 + scol, gB + it * 2048);
            gload_lds16(Wv + (size_t)row * 512 + k0 + scol, vB + it * 2048);
        }
        __syncthreads();
        const int krow = lane & 15;
        const int sw = krow & 7;
#pragma unroll
        for (int kk = 0; kk < BK; kk += 32) {
            const int kcol = kk + ((lane >> 4) << 3);
            const int koff = (((kcol >> 3) ^ sw) << 3);
            s16x8 af[4], bg[4], bv[4];
#pragma unroll
            for (int i = 0; i < 4; ++i)
                af[i] = *(const s16x8*)(&As[wm + i * 16 + krow][koff]);
#pragma unroll
            for (int j = 0; j < 4; ++j) {
                bg[j] = *(const s16x8*)(&Bg[wn + j * 16 + krow][koff]);
                bv[j] = *(const s16x8*)(&Bv[wn + j * 16 + krow][koff]);
            }
#pragma unroll
            for (int i = 0; i < 4; ++i)
#pragma unroll
                for (int j = 0; j < 4; ++j) {
                    accg[i][j] = __builtin_amdgcn_mfma_f32_16x16x32_bf16(af[i], bg[j], accg[i][j], 0, 0, 0);
                    accv[i][j] = __builtin_amdgcn_mfma_f32_16x16x32_bf16(af[i], bv[j], accv[i][j], 0, 0, 0);
                }
        }
    }

    const int col_l = lane & 15;
    const int row_q = (lane >> 4) * 4;
#pragma unroll
    for (int j = 0; j < 4; ++j) {
        const int col = n0 + wn + j * 16 + col_l;
        const float bg_ = b2[col];
        const float bv_ = b2[col + 512];
#pragma unroll
        for (int i = 0; i < 4; ++i) {
#pragma unroll
            for (int r = 0; r < 4; ++r) {
                const int row = m0 + wm + i * 16 + row_q + r;
                const float gval = sigmoidf_(accg[i][j][r] + bg_);
                const float vval = accv[i][j][r] + bv_;
                out[(size_t)row * 512 + col] = f2b(gval * vval);
            }
        }
    }
}

extern "C" void kernel_launch(void* const* d_in, const int* in_sizes, int n_in,
                              void* d_out, int out_size, void* d_ws, size_t ws_size,
                              hipStream_t stream)
{
    const int*   x      = (const int*)d_in[0];
    const float* ln_g   = (const float*)d_in[1];
    const float* ln_b   = (const float*)d_in[2];
    const float* conv_w = (const float*)d_in[3];
    const float* conv_b = (const float*)d_in[4];
    const float* wg     = (const float*)d_in[5];
    const float* bg     = (const float*)d_in[6];
    const float* wout   = (const float*)d_in[7];
    const float* bout   = (const float*)d_in[8];
    const float* fc_w   = (const float*)d_in[9];
    const float* fc_b   = (const float*)d_in[10];
    const float* mo_w   = (const float*)d_in[11];
    const float* mo_b   = (const float*)d_in[12];
    const float* lnf_g  = (const float*)d_in[13];
    const float* lnf_b  = (const float*)d_in[14];
    const float* head_w = (const float*)d_in[15];
    const float* head_b = (const float*)d_in[16];

    if (ws_size < WS_NEED) {
        sentinel_kernel<<<1, 256, 0, stream>>>((float*)d_out);
        return;
    }

    char* ws = (char*)d_ws;
    u16*   y    = (u16*)(ws + Y_OFF);         // bf16 residual stream
    u16*   apad = (u16*)(ws + APAD_OFF);
    u16*   z2b  = (u16*)(ws + Z2_OFF);        // conv out bf16; gv (gated) overlaps after scan
    u16*   gv   = (u16*)(ws + Z2_OFF);
    u16*   hs   = (u16*)(ws + HS_OFF);        // scan out; final-LN out reuses
    float* gbuf = (float*)(ws + G_OFF);
    float* b2   = (float*)(ws + B2_OFF);
    float* Abuf = (float*)(ws + ABUF_OFF);
    float* Hloc = (float*)(ws + HLOC_OFF);
    float* Hst  = (float*)(ws + HST_OFF);
    u16*   wcv  = (u16*)(ws + WCV_OFF);
    u16*   wmo  = (u16*)(ws + WMO_OFF);
    u16*   whd  = (u16*)(ws + WHD_OFF);
    u16*   woT  = (u16*)(ws + WOT_OFF);
    u16*   wfcb = (u16*)(ws + WFCB_OFF);
    u16*   wc   = (u16*)(ws + WC_OFF);

    // merged weight conversion + Wc precompute
    prep_kernel<<<PN5 / 256, 256, 0, stream>>>(conv_w, mo_w, head_w, fc_w, wout,
                                               wcv, wmo, whd, wfcb, woT);
    gemm_bt<<<dim3(8, 4, 4), 256, 0, stream>>>(wfcb, woT, nullptr, nullptr,
            nullptr, wc, 512, 512, 512, 0, 1024*512, 512*512, 1024*512);
    bias2_kernel<<<(NL_*1024)/4, 256, 0, stream>>>(fc_w, bout, fc_b, b2);

    embed_kernel<<<(TOK_*D_/8)/256, 256, 0, stream>>>(x, y);

    for (int l = 0; l < NL_; ++l) {
        // ln with 8 extra blocks zeroing the conv pad rows
        ln_kernel<<<TOK_/4 + 8, 256, 0, stream>>>(y, ln_g + l*512, ln_b + l*512, apad, 1);
        // conv1d as im2col GEMM: K=1536, lda=512 (rows overlap), bf16 out z2b
        gemm_bt<<<dim3(256, 4), 256, 0, stream>>>(apad, wcv + (size_t)l*512*1536,
                conv_b + l*512, nullptr, nullptr, z2b, 512, 1536, 512, 1, 0, 0, 0);
        // fused gate + scan pass 1
        scan1g_kernel<<<B_*CH_, 256, 0, stream>>>(z2b, wg + l*512, bg + l, gbuf, Abuf, Hloc);
        scan2_kernel<<<(B_*D_)/256, 256, 0, stream>>>(Abuf, Hloc, Hst);
        scan3_kernel<<<(B_*CH_*D_)/256, 256, 0, stream>>>(z2b, gbuf, Hst, hs);
        // merged wout+fc GEMM with fused sigmoid-gate; writes gv (z2 region, z2 dead)
        gemm_fc<<<dim3(256, 4), 256, 0, stream>>>(hs, wc + (size_t)l*1024*512,
                b2 + l*1024, gv);
        // mo: bf16 residual read+write on y
        gemm_bt<<<dim3(256, 4), 256, 0, stream>>>(gv, wmo + (size_t)l*512*512,
                mo_b + l*512, y, nullptr, y, 512, 512, 512, 0, 0, 0, 0);
    }

    // final LN (bf16 into hs, dead) + head GEMM -> d_out fp32
    ln_kernel<<<TOK_/4, 256, 0, stream>>>(y, lnf_g, lnf_b, hs, 0);
    gemm_bt<<<dim3(256, 4), 256, 0, stream>>>(hs, whd, head_b, nullptr,
            (float*)d_out, nullptr, 512, 512, 512, 0, 0, 0, 0);

    (void)in_sizes; (void)n_in; (void)out_size;
}